// Round 10
// baseline (736.406 us; speedup 1.0000x reference)
//
#include <hip/hip_runtime.h>

#define NN 100000   // nodes
#define NE 1600000  // edges
#define IN_CH 41
#define EDIM 8
#define H 64
#define GNUM 256
#define ATOM 21
#define EPSV 1e-5f
#define EPW 16      // edges per wave-chunk in aggr
#define NTILE (NN / 16)   // 6250 node tiles (exact)

#define BDST2 8     // dst rows per aggr wave (exclusive ownership)
#define NBK2 12500  // NN / 8, exact
#define NBLK_S ((NN + 1023) / 1024)        // 98 scan blocks

typedef unsigned short u16;
typedef unsigned int u32;
typedef unsigned long long u64;
typedef __attribute__((ext_vector_type(8))) short short8;
typedef __attribute__((ext_vector_type(4))) float floatx4;

__device__ __forceinline__ u16 f2bf(float f) {
    u32 u = __float_as_uint(f);
    u32 r = (u + 0x7FFFu + ((u >> 16) & 1u)) >> 16;   // RNE
    return (u16)r;
}
__device__ __forceinline__ float bf2f(u16 u) {
    return __uint_as_float(((u32)u) << 16);
}
__device__ __forceinline__ floatx4 mfma16(short8 a, short8 b, floatx4 c) {
    return __builtin_amdgcn_mfma_f32_16x16x32_bf16(a, b, c, 0, 0, 0);
}
__device__ __forceinline__ short8 pack_bf8(float4 a, float4 b) {
    short8 s;
    s[0] = (short)f2bf(a.x); s[1] = (short)f2bf(a.y);
    s[2] = (short)f2bf(a.z); s[3] = (short)f2bf(a.w);
    s[4] = (short)f2bf(b.x); s[5] = (short)f2bf(b.y);
    s[6] = (short)f2bf(b.z); s[7] = (short)f2bf(b.w);
    return s;
}

// ---- partition: mask per node -> lig_list / prot_list ----------------------
__global__ __launch_bounds__(256) void partition_kernel(
    const float* __restrict__ x, int* __restrict__ ctr,
    int* __restrict__ lig_list, int* __restrict__ prot_list)
{
    const int n = blockIdx.x * 256 + threadIdx.x;
    const int lane = threadIdx.x & 63;
    float m = 0.0f;
    if (n < NN) {
        const float* xr = x + (size_t)n * IN_CH + ATOM;
#pragma unroll
        for (int d = 0; d < IN_CH - ATOM; ++d) m += fabsf(xr[d]);
    }
    const bool valid = n < NN;
    const bool prot = valid && (m > 1e-6f);
    const bool lig = valid && !prot;

    const u64 bl = __ballot(lig);
    const u64 bp = __ballot(prot);
    const u64 below_m = (lane == 63) ? (~0ull >> 1) : ((1ull << lane) - 1ull);
    int base_l = 0, base_p = 0;
    if (lane == 0) {
        if (bl) base_l = atomicAdd(&ctr[0], (int)__popcll(bl));
        if (bp) base_p = atomicAdd(&ctr[1], (int)__popcll(bp));
    }
    base_l = __shfl(base_l, 0, 64);
    base_p = __shfl(base_p, 0, 64);
    if (lig)  lig_list [base_l + (int)__popcll(bl & below_m)] = n;
    if (prot) prot_list[base_p + (int)__popcll(bp & below_m)] = n;
}

// ---- xb: zero-padded bf16 copy of x [NN x 64] ------------------------------
__global__ __launch_bounds__(256) void xb_kernel(
    const float* __restrict__ x, u16* __restrict__ xb)
{
    const int id = blockIdx.x * 256 + threadIdx.x;
    if (id >= NN * H) return;
    const int n = id >> 6, d = id & 63;
    xb[id] = (d < IN_CH) ? f2bf(x[(size_t)n * IN_CH + d]) : (u16)0;
}

// ---- ea -> bf16x8 in original edge order (fully coalesced) -----------------
__global__ __launch_bounds__(256) void ea2b_kernel(
    const float* __restrict__ ea, uint4* __restrict__ eab16g)
{
    const int e = blockIdx.x * 256 + threadIdx.x;
    if (e >= NE) return;
    const float4* e4 = (const float4*)(ea + (size_t)e * EDIM);
    const float4 a = e4[0], b = e4[1];
    uint4 u;
    u.x = (u32)f2bf(a.x) | ((u32)f2bf(a.y) << 16);
    u.y = (u32)f2bf(a.z) | ((u32)f2bf(a.w) << 16);
    u.z = (u32)f2bf(b.x) | ((u32)f2bf(b.y) << 16);
    u.w = (u32)f2bf(b.z) | ((u32)f2bf(b.w) << 16);
    eab16g[e] = u;
}

// ---- prep: swizzle 10 weight matrices into MFMA B-fragment order -----------
__global__ __launch_bounds__(256) void prep_w_kernel(
    const float* __restrict__ ligW1, const float* __restrict__ ligW2,
    const float* __restrict__ protW1, const float* __restrict__ protW2,
    const float* __restrict__ convW1, const float* __restrict__ convW2,
    u16* __restrict__ wf)
{
    const int id = blockIdx.x * 256 + threadIdx.x;
    if (id >= 10 * 4096) return;
    const int j = id & 7, l = (id >> 3) & 63, t = (id >> 9) & 3;
    const int c = (id >> 11) & 1, mat = id >> 12;
    const int k = c * 32 + ((l >> 4) * 8) + j;
    const int n = t * 16 + (l & 15);
    const float* src; int K = 64;
    if (mat == 0)      { src = ligW1;  K = IN_CH; }
    else if (mat == 1) { src = ligW2; }
    else if (mat == 2) { src = protW1; K = IN_CH; }
    else if (mat == 3) { src = protW2; }
    else {
        const int layer = (mat - 4) >> 1;
        src = (((mat - 4) & 1) ? convW2 : convW1) + (size_t)layer * H * H;
    }
    wf[id] = (k < K) ? f2bf(src[(size_t)k * H + n]) : (u16)0;
}

// ---- MFMA MLP over a gathered node list (encoder) --------------------------
__global__ __launch_bounds__(256) void enc_mfma_kernel(
    const int* __restrict__ list, const int* __restrict__ countPtr,
    const u16* __restrict__ xb,
    const u16* __restrict__ w1f, const u16* __restrict__ w2f,
    const float* __restrict__ bia1, const float* __restrict__ bia2,
    float* __restrict__ h, u16* __restrict__ h16)
{
    __shared__ __align__(16) u16 hid[4][16 * 72];
    const int wv = threadIdx.x >> 6;
    const int lane = threadIdx.x & 63;
    const int tile = blockIdx.x * 4 + wv;
    const int count = *countPtr;
    if (tile * 16 >= count) return;
    const int quad = lane >> 4;
    const int mi = lane & 15;
    int idx = tile * 16 + mi;
    if (idx >= count) idx = count - 1;
    const int nid = list[idx];

    const short8 a0 = *(const short8*)(xb + (size_t)nid * H + quad * 8);
    const short8 a1 = *(const short8*)(xb + (size_t)nid * H + 32 + quad * 8);

    floatx4 acc[4];
#pragma unroll
    for (int t = 0; t < 4; ++t) acc[t] = (floatx4){0.f, 0.f, 0.f, 0.f};
#pragma unroll
    for (int t = 0; t < 4; ++t) {
        const short8 b0 = *(const short8*)(w1f + ((size_t)(0 * 4 + t) * 64 + lane) * 8);
        const short8 b1 = *(const short8*)(w1f + ((size_t)(1 * 4 + t) * 64 + lane) * 8);
        acc[t] = mfma16(a0, b0, acc[t]);
        acc[t] = mfma16(a1, b1, acc[t]);
    }

    u16* myh = hid[wv];
#pragma unroll
    for (int t = 0; t < 4; ++t) {
        const float bv = bia1[t * 16 + mi];
#pragma unroll
        for (int r = 0; r < 4; ++r) {
            const float v = fmaxf(acc[t][r] + bv, 0.0f);
            myh[(quad * 4 + r) * 72 + t * 16 + mi] = f2bf(v);
        }
    }
    asm volatile("s_waitcnt lgkmcnt(0)" ::: "memory");

    const short8 c0 = *(const short8*)(myh + mi * 72 + quad * 8);
    const short8 c1 = *(const short8*)(myh + mi * 72 + 32 + quad * 8);

    floatx4 acc2[4];
#pragma unroll
    for (int t = 0; t < 4; ++t) acc2[t] = (floatx4){0.f, 0.f, 0.f, 0.f};
#pragma unroll
    for (int t = 0; t < 4; ++t) {
        const short8 b0 = *(const short8*)(w2f + ((size_t)(0 * 4 + t) * 64 + lane) * 8);
        const short8 b1 = *(const short8*)(w2f + ((size_t)(1 * 4 + t) * 64 + lane) * 8);
        acc2[t] = mfma16(c0, b0, acc2[t]);
        acc2[t] = mfma16(c1, b1, acc2[t]);
    }

#pragma unroll
    for (int t = 0; t < 4; ++t) {
        const float bv = bia2[t * 16 + mi];
#pragma unroll
        for (int r = 0; r < 4; ++r) {
            const int row = quad * 4 + r;
            const int nr = __shfl(nid, row, 64);
            if (tile * 16 + row < count) {
                const float v = fmaxf(acc2[t][r] + bv, 0.0f);
                h[(size_t)nr * H + t * 16 + mi] = v;
                h16[(size_t)nr * H + t * 16 + mi] = f2bf(v);
            }
        }
    }
}

// ---- MFMA MLP over consecutive nodes, in place (conv nn), no outer relu ----
__global__ __launch_bounds__(256) void mlp_mfma_kernel(
    const u16* __restrict__ w1f, const u16* __restrict__ w2f,
    const float* __restrict__ bia1, const float* __restrict__ bia2,
    float* __restrict__ h)
{
    __shared__ __align__(16) u16 hid[4][16 * 72];
    const int wv = threadIdx.x >> 6;
    const int lane = threadIdx.x & 63;
    const int tile = blockIdx.x * 4 + wv;
    if (tile >= NTILE) return;
    const int quad = lane >> 4;
    const int mi = lane & 15;
    const int row = tile * 16 + mi;
    const float* zr = h + (size_t)row * H;

    const float4 f0 = *(const float4*)(zr + quad * 8);
    const float4 f1 = *(const float4*)(zr + quad * 8 + 4);
    const float4 f2 = *(const float4*)(zr + 32 + quad * 8);
    const float4 f3 = *(const float4*)(zr + 32 + quad * 8 + 4);
    const short8 a0 = pack_bf8(f0, f1);
    const short8 a1 = pack_bf8(f2, f3);

    floatx4 acc[4];
#pragma unroll
    for (int t = 0; t < 4; ++t) acc[t] = (floatx4){0.f, 0.f, 0.f, 0.f};
#pragma unroll
    for (int t = 0; t < 4; ++t) {
        const short8 b0 = *(const short8*)(w1f + ((size_t)(0 * 4 + t) * 64 + lane) * 8);
        const short8 b1 = *(const short8*)(w1f + ((size_t)(1 * 4 + t) * 64 + lane) * 8);
        acc[t] = mfma16(a0, b0, acc[t]);
        acc[t] = mfma16(a1, b1, acc[t]);
    }

    u16* myh = hid[wv];
#pragma unroll
    for (int t = 0; t < 4; ++t) {
        const float bv = bia1[t * 16 + mi];
#pragma unroll
        for (int r = 0; r < 4; ++r) {
            const float v = fmaxf(acc[t][r] + bv, 0.0f);
            myh[(quad * 4 + r) * 72 + t * 16 + mi] = f2bf(v);
        }
    }
    asm volatile("s_waitcnt lgkmcnt(0)" ::: "memory");

    const short8 c0 = *(const short8*)(myh + mi * 72 + quad * 8);
    const short8 c1 = *(const short8*)(myh + mi * 72 + 32 + quad * 8);

    floatx4 acc2[4];
#pragma unroll
    for (int t = 0; t < 4; ++t) acc2[t] = (floatx4){0.f, 0.f, 0.f, 0.f};
#pragma unroll
    for (int t = 0; t < 4; ++t) {
        const short8 b0 = *(const short8*)(w2f + ((size_t)(0 * 4 + t) * 64 + lane) * 8);
        const short8 b1 = *(const short8*)(w2f + ((size_t)(1 * 4 + t) * 64 + lane) * 8);
        acc2[t] = mfma16(c0, b0, acc2[t]);
        acc2[t] = mfma16(c1, b1, acc2[t]);
    }

#pragma unroll
    for (int t = 0; t < 4; ++t) {
        const float bv = bia2[t * 16 + mi];
#pragma unroll
        for (int r = 0; r < 4; ++r) {
            const int orow = tile * 16 + quad * 4 + r;
            h[(size_t)orow * H + t * 16 + mi] = acc2[t][r] + bv;
        }
    }
}

// ---------------- per-graph node ranges (batch is sorted) -------------------
__global__ void bounds_kernel(const int* __restrict__ batch, int* __restrict__ start)
{
    int g = blockIdx.x * blockDim.x + threadIdx.x;
    if (g > GNUM) return;
    int lo = 0, hi = NN;
    while (lo < hi) {
        int mid = (lo + hi) >> 1;
        if (batch[mid] < g) lo = mid + 1; else hi = mid;
    }
    start[g] = lo;
}

// ---- per-dst histogram straight into global (400 KB, L2-resident) ----------
__global__ __launch_bounds__(256) void bhist_kernel(
    const int* __restrict__ ei, int* __restrict__ gbcount)
{
    const int e = blockIdx.x * 256 + threadIdx.x;
    if (e < NE) atomicAdd(&gbcount[ei[NE + e]], 1);
}

// ---- exclusive scan of NN per-dst counts: 2-kernel scan --------------------
__global__ __launch_bounds__(1024) void scanA_kernel(
    const int* __restrict__ gbcount, int* __restrict__ gstart, int* __restrict__ gsums)
{
    __shared__ int s[1024];
    const int t = threadIdx.x;
    const int idx = blockIdx.x * 1024 + t;
    const int v = (idx < NN) ? gbcount[idx] : 0;
    s[t] = v;
    __syncthreads();
#pragma unroll
    for (int off = 1; off < 1024; off <<= 1) {
        int tmp = (t >= off) ? s[t - off] : 0;
        __syncthreads();
        s[t] += tmp;
        __syncthreads();
    }
    if (idx < NN) gstart[idx] = s[t] - v;       // block-local exclusive
    if (t == 1023) gsums[blockIdx.x] = s[1023]; // block total
}

__global__ __launch_bounds__(1024) void scanB_kernel(
    int* __restrict__ gstart, int* __restrict__ gcur, const int* __restrict__ gsums)
{
    __shared__ int sm[128];
    __shared__ int off_s;
    const int t = threadIdx.x;
    const int b = blockIdx.x;
    if (t < NBLK_S) sm[t] = gsums[t];
    __syncthreads();
    if (t == 0) {
        int o = 0;
        for (int i = 0; i < b; ++i) o += sm[i];
        off_s = o;
    }
    __syncthreads();
    const int idx = b * 1024 + t;
    if (idx < NN) {
        const int g = gstart[idx] + off_s;
        gstart[idx] = g;
        gcur[idx] = g;
    }
    if (b == 0 && t == 0) gstart[NN] = NE;
}

// ---- full counting sort in ONE pass: per-dst global cursor scatter ---------
// Output is fully dst-sorted (grouped per dst; order within a run arbitrary).
// Record: bits[16:0] = src, bits[19:17] = dst & 7 (for run detection in aggr).
__global__ __launch_bounds__(256) void p1_kernel(
    const int* __restrict__ ei, const uint4* __restrict__ eab16g,
    int* __restrict__ gcur,
    u32* __restrict__ brec, uint4* __restrict__ bfeat)
{
    const int e = blockIdx.x * 256 + threadIdx.x;
    if (e >= NE) return;
    const int dst = ei[NE + e];
    const int pos = atomicAdd(&gcur[dst], 1);
    brec[pos] = (u32)ei[e] | ((u32)(dst & (BDST2 - 1)) << 17);
    bfeat[pos] = eab16g[e];
}

// ---- edge aggregation: one WAVE per 8-dst bucket over SORTED edges ---------
// Edges grouped by dst -> single-register run-accumulate (the proven 603-us-
// baseline inner loop), zero atomics in the hot path. Flushes use non-
// returning unsafeAtomicAdd (no read -> no stall); exclusive bucket ownership
// makes them race-free anyway. __launch_bounds__(256,4) gives the register
// allocator headroom (round-4's VGPR=28 proved hv[16] was NOT kept live ->
// serialized per-edge gather latency).
__global__ __launch_bounds__(256, 4) void aggr_kernel(
    const u32* __restrict__ brec,
    const u32* __restrict__ bfeat32,
    const int* __restrict__ gstart,
    const float* __restrict__ We, const float* __restrict__ be,
    const u16* __restrict__ h16, float* __restrict__ h)
{
    const int lane = threadIdx.x & 63;
    const int bk = blockIdx.x * 4 + (threadIdx.x >> 6);   // bucket = wave
    const int row0 = bk * BDST2;
    const int s = gstart[row0], e = gstart[row0 + BDST2];
    if (s >= e) return;

    float we_r[EDIM];
#pragma unroll
    for (int d = 0; d < EDIM; ++d) we_r[d] = We[d * H + lane];
    const float be_r = be[lane];

    float acc = 0.0f;
    int cur = -1;

    for (int base = s; base < e; base += EPW) {
        const int cnt = min(EPW, e - base);     // wave-uniform
        u32 rec = 0;
        if ((lane & 15) < cnt) rec = brec[base + (lane & 15)];
        u32 eu = 0;
        if (lane < cnt * 4) eu = bfeat32[(size_t)base * 4 + lane];

        float hv[EPW];
#pragma unroll
        for (int j = 0; j < EPW; ++j) {
            const int sj = (int)(__builtin_amdgcn_readlane(rec, j) & 0x1ffffu);
            hv[j] = bf2f(h16[(size_t)sj * H + lane]);   // rec=0 for tail -> safe
        }
#pragma unroll
        for (int j = 0; j < EPW; ++j) {
            if (j < cnt) {                      // wave-uniform
                const u32 rj = __builtin_amdgcn_readlane(rec, j);
                const int ld = (int)(rj >> 17);
                float msg = be_r;
#pragma unroll
                for (int p = 0; p < 4; ++p) {
                    const u32 w2 = __builtin_amdgcn_readlane(eu, j * 4 + p);
                    msg = fmaf(__uint_as_float(w2 << 16), we_r[2 * p], msg);
                    msg = fmaf(__uint_as_float(w2 & 0xffff0000u), we_r[2 * p + 1], msg);
                }
                const float val = fmaxf(hv[j] + msg, 0.0f);
                if (ld != cur) {                // wave-uniform, rare (runs ~16)
                    if (cur >= 0)
                        unsafeAtomicAdd(&h[(size_t)(row0 + cur) * H + lane], acc);
                    acc = 0.0f;
                    cur = ld;
                }
                acc += val;
            }
        }
    }
    unsafeAtomicAdd(&h[(size_t)(row0 + cur) * H + lane], acc);
}

// ------- GraphNorm + relu, in place; refresh h16; optional pool accum -------
__global__ __launch_bounds__(1024) void graphnorm_kernel(
    float* __restrict__ h, u16* __restrict__ h16,
    const int* __restrict__ start,
    const float* __restrict__ w, const float* __restrict__ b,
    const float* __restrict__ a,
    float* __restrict__ pool, int do_pool)
{
    __shared__ float red1[16][H], red2[16][H];
    __shared__ float amean_s[H], rstd_s[H];
    const int g = blockIdx.x;
    const int lane = threadIdx.x & 63;
    const int wv = threadIdx.x >> 6;
    const int s = start[g], e = start[g + 1];

    float s1 = 0.f, s2 = 0.f;
    for (int i = s + wv; i < e; i += 16) {
        float v = h[(size_t)i * H + lane];
        s1 += v; s2 += v * v;
    }
    red1[wv][lane] = s1; red2[wv][lane] = s2;
    __syncthreads();
    if (threadIdx.x < H) {
        float t1 = 0.f, t2 = 0.f;
#pragma unroll
        for (int k = 0; k < 16; ++k) { t1 += red1[k][lane]; t2 += red2[k][lane]; }
        float cnt = fmaxf((float)(e - s), 1.0f);
        float mean = t1 / cnt;
        float alpha = a[lane];
        float var = t2 / cnt - (2.0f * alpha - alpha * alpha) * mean * mean;
        var = fmaxf(var, 0.0f);
        amean_s[lane] = alpha * mean;
        rstd_s[lane] = rsqrtf(var + EPSV);
    }
    __syncthreads();
    const float am = amean_s[lane], rstd = rstd_s[lane];
    const float ww = w[lane], bb = b[lane];
    float ps = 0.f;
    for (int i = s + wv; i < e; i += 16) {
        float v = (h[(size_t)i * H + lane] - am) * rstd * ww + bb;
        v = fmaxf(v, 0.0f);
        h[(size_t)i * H + lane] = v;
        h16[(size_t)i * H + lane] = f2bf(v);
        ps += v;
    }
    if (do_pool && e > s) unsafeAtomicAdd(&pool[g * H + lane], ps);
}

// ---------------- readout from pooled sums ----------------------------------
__global__ __launch_bounds__(64) void final_kernel(
    const float* __restrict__ pool,
    const float* __restrict__ W1, const float* __restrict__ b1,
    const float* __restrict__ W2, const float* __restrict__ b2,
    float* __restrict__ out)
{
    const int g = blockIdx.x;
    const int lane = threadIdx.x;
    const float gv = pool[g * H + lane];
    float acc = b1[lane];
#pragma unroll
    for (int d = 0; d < H; ++d)
        acc = fmaf(__shfl(gv, d, 64), W1[d * H + lane], acc);
    float r = fmaxf(acc, 0.0f);
    float v = r * W2[lane];
#pragma unroll
    for (int o = 32; o > 0; o >>= 1) v += __shfl_xor(v, o, 64);
    if (lane == 0) out[g] = v + b2[0];
}

extern "C" void kernel_launch(void* const* d_in, const int* in_sizes, int n_in,
                              void* d_out, int out_size, void* d_ws, size_t ws_size,
                              hipStream_t stream)
{
    const float* x      = (const float*)d_in[0];
    const int*   ei     = (const int*)  d_in[1];
    const float* ea     = (const float*)d_in[2];
    const int*   batch  = (const int*)  d_in[3];
    const float* ligW1  = (const float*)d_in[4];
    const float* ligb1  = (const float*)d_in[5];
    const float* ligW2  = (const float*)d_in[6];
    const float* ligb2  = (const float*)d_in[7];
    const float* protW1 = (const float*)d_in[8];
    const float* protb1 = (const float*)d_in[9];
    const float* protW2 = (const float*)d_in[10];
    const float* protb2 = (const float*)d_in[11];
    const float* convWe = (const float*)d_in[12];
    const float* convbe = (const float*)d_in[13];
    const float* convW1 = (const float*)d_in[14];
    const float* convb1 = (const float*)d_in[15];
    const float* convW2 = (const float*)d_in[16];
    const float* convb2 = (const float*)d_in[17];
    const float* normw  = (const float*)d_in[18];
    const float* normb  = (const float*)d_in[19];
    const float* norma  = (const float*)d_in[20];
    const float* outW1  = (const float*)d_in[21];
    const float* outb1  = (const float*)d_in[22];
    const float* outW2  = (const float*)d_in[23];
    const float* outb2  = (const float*)d_in[24];

    float* out = (float*)d_out;

    // -------- workspace layout (16B-aligned blocks first) -------------------
    float* h         = (float*)d_ws;                    // NN*H f32      25.6 MB
    uint4* bfeat     = (uint4*)(h + (size_t)NN * H);    // NE uint4      25.6 MB
    u32*   brec      = (u32*)(bfeat + (size_t)NE);      // NE u32         6.4 MB
    u16*   h16       = (u16*)(brec + (size_t)NE);       // NN*H u16      12.8 MB
    u16*   xb        = h16 + (size_t)NN * H;            // NN*H u16      12.8 MB
    u16*   wf        = xb + (size_t)NN * H;             // 40960 u16     80 KB
    uint4* eab16g    = (uint4*)h16;                     // NE uint4 (overlay h16+xb)

    int*   ctr       = (int*)(wf + 40960);              // 2     (zeroed)
    int*   gbcount   = ctr + 2;                         // NN    (zeroed)
    float* pool      = (float*)(gbcount + NN);          // GNUM*H (zeroed)
    int*   gstart    = (int*)(pool + GNUM * H);         // NN+1  (full CSR rowstart)
    int*   gcur      = gstart + (NN + 1);               // NN
    int*   gsums     = gcur + NN;                       // 128
    int*   start     = gsums + 128;                     // GNUM+1
    int*   lig_list  = start + (GNUM + 1);              // NN
    int*   prot_list = lig_list + NN;                   // NN

    hipMemsetAsync(ctr, 0, ((size_t)2 + NN + GNUM * H) * sizeof(int), stream);

    // ---- prep not touching overlays ----
    prep_w_kernel<<<(10 * 4096 + 255) / 256, 256, 0, stream>>>(
        ligW1, ligW2, protW1, protW2, convW1, convW2, wf);
    partition_kernel<<<(NN + 255) / 256, 256, 0, stream>>>(x, ctr, lig_list, prot_list);
    bounds_kernel<<<2, 256, 0, stream>>>(batch, start);

    // ---- full counting sort: global hist -> 2-kernel scan -> direct scatter
    bhist_kernel<<<NE / 256, 256, 0, stream>>>(ei, gbcount);
    scanA_kernel<<<NBLK_S, 1024, 0, stream>>>(gbcount, gstart, gsums);
    scanB_kernel<<<NBLK_S, 1024, 0, stream>>>(gstart, gcur, gsums);
    ea2b_kernel<<<(NE + 255) / 256, 256, 0, stream>>>(ea, eab16g);
    p1_kernel<<<NE / 256, 256, 0, stream>>>(ei, eab16g, gcur, brec, bfeat);

    // ---- xb after eab16g overlay is dead; then encoder ----
    xb_kernel<<<(NN * H + 255) / 256, 256, 0, stream>>>(x, xb);
    const int enc_blocks = (NTILE + 3) / 4;
    enc_mfma_kernel<<<enc_blocks, 256, 0, stream>>>(
        lig_list, &ctr[0], xb, wf + 0 * 4096, wf + 1 * 4096, ligb1, ligb2, h, h16);
    enc_mfma_kernel<<<enc_blocks, 256, 0, stream>>>(
        prot_list, &ctr[1], xb, wf + 2 * 4096, wf + 3 * 4096, protb1, protb2, h, h16);

    const int aggr_blocks = NBK2 / 4;   // 3125, exact (one wave per 8-dst bucket)
    const int mlp_blocks = (NTILE + 3) / 4;
    for (int l = 0; l < 3; ++l) {
        aggr_kernel<<<aggr_blocks, 256, 0, stream>>>(
            brec, (const u32*)bfeat, gstart,
            convWe + (size_t)l * EDIM * H, convbe + (size_t)l * H, h16, h);
        mlp_mfma_kernel<<<mlp_blocks, 256, 0, stream>>>(
            wf + (size_t)(4 + 2 * l) * 4096, wf + (size_t)(5 + 2 * l) * 4096,
            convb1 + (size_t)l * H, convb2 + (size_t)l * H, h);
        graphnorm_kernel<<<GNUM, 1024, 0, stream>>>(
            h, h16, start, normw + (size_t)l * H, normb + (size_t)l * H,
            norma + (size_t)l * H, pool, (l == 2) ? 1 : 0);
    }
    final_kernel<<<GNUM, 64, 0, stream>>>(pool, outW1, outb1, outW2, outb2, out);
}

// Round 11
// 635.330 us; speedup vs baseline: 1.1591x; 1.1591x over previous
//
#include <hip/hip_runtime.h>

#define NN 100000   // nodes
#define NE 1600000  // edges
#define IN_CH 41
#define EDIM 8
#define H 64
#define GNUM 256
#define ATOM 21
#define EPSV 1e-5f
#define EPW 16      // edges per wave-chunk in aggr
#define NTILE (NN / 16)   // 6250 node tiles (exact)

#define BSH 7       // coarse bucket shift: dst>>7, 128 dst per bucket
#define BDST 128    // dst per coarse bucket
#define NBK 782     // ceil(NN / 128)
#define GRP 16      // 8-dst groups per coarse bucket (128/8)
#define BDST2 8     // dst rows per aggr wave (exclusive ownership)
#define NAGG 12500  // NN / 8, exact (aggr buckets)
#define SCAP 3584   // sort stage capacity (mean 2046, +34 sigma)

#define VPT_H 8
#define EPB_H (1024 * VPT_H)               // 8192 edges/block (bhist)
#define NBLK_H ((NE + EPB_H - 1) / EPB_H)  // 196
#define VPT_P1 16
#define EPB_P1 (1024 * VPT_P1)             // 16384 edges/block (p1)
#define NBLK_P1 ((NE + EPB_P1 - 1) / EPB_P1)  // 98

typedef unsigned short u16;
typedef unsigned int u32;
typedef unsigned long long u64;
typedef __attribute__((ext_vector_type(8))) short short8;
typedef __attribute__((ext_vector_type(4))) float floatx4;

__device__ __forceinline__ u16 f2bf(float f) {
    u32 u = __float_as_uint(f);
    u32 r = (u + 0x7FFFu + ((u >> 16) & 1u)) >> 16;   // RNE
    return (u16)r;
}
__device__ __forceinline__ float bf2f(u16 u) {
    return __uint_as_float(((u32)u) << 16);
}
__device__ __forceinline__ floatx4 mfma16(short8 a, short8 b, floatx4 c) {
    return __builtin_amdgcn_mfma_f32_16x16x32_bf16(a, b, c, 0, 0, 0);
}
__device__ __forceinline__ short8 pack_bf8(float4 a, float4 b) {
    short8 s;
    s[0] = (short)f2bf(a.x); s[1] = (short)f2bf(a.y);
    s[2] = (short)f2bf(a.z); s[3] = (short)f2bf(a.w);
    s[4] = (short)f2bf(b.x); s[5] = (short)f2bf(b.y);
    s[6] = (short)f2bf(b.z); s[7] = (short)f2bf(b.w);
    return s;
}

// ---- partition: mask per node -> lig_list / prot_list ----------------------
__global__ __launch_bounds__(256) void partition_kernel(
    const float* __restrict__ x, int* __restrict__ ctr,
    int* __restrict__ lig_list, int* __restrict__ prot_list)
{
    const int n = blockIdx.x * 256 + threadIdx.x;
    const int lane = threadIdx.x & 63;
    float m = 0.0f;
    if (n < NN) {
        const float* xr = x + (size_t)n * IN_CH + ATOM;
#pragma unroll
        for (int d = 0; d < IN_CH - ATOM; ++d) m += fabsf(xr[d]);
    }
    const bool valid = n < NN;
    const bool prot = valid && (m > 1e-6f);
    const bool lig = valid && !prot;

    const u64 bl = __ballot(lig);
    const u64 bp = __ballot(prot);
    const u64 below_m = (lane == 63) ? (~0ull >> 1) : ((1ull << lane) - 1ull);
    int base_l = 0, base_p = 0;
    if (lane == 0) {
        if (bl) base_l = atomicAdd(&ctr[0], (int)__popcll(bl));
        if (bp) base_p = atomicAdd(&ctr[1], (int)__popcll(bp));
    }
    base_l = __shfl(base_l, 0, 64);
    base_p = __shfl(base_p, 0, 64);
    if (lig)  lig_list [base_l + (int)__popcll(bl & below_m)] = n;
    if (prot) prot_list[base_p + (int)__popcll(bp & below_m)] = n;
}

// ---- xb: zero-padded bf16 copy of x [NN x 64] ------------------------------
__global__ __launch_bounds__(256) void xb_kernel(
    const float* __restrict__ x, u16* __restrict__ xb)
{
    const int id = blockIdx.x * 256 + threadIdx.x;
    if (id >= NN * H) return;
    const int n = id >> 6, d = id & 63;
    xb[id] = (d < IN_CH) ? f2bf(x[(size_t)n * IN_CH + d]) : (u16)0;
}

// ---- ea -> bf16x8 in original edge order (fully coalesced) -----------------
__global__ __launch_bounds__(256) void ea2b_kernel(
    const float* __restrict__ ea, uint4* __restrict__ eab16g)
{
    const int e = blockIdx.x * 256 + threadIdx.x;
    if (e >= NE) return;
    const float4* e4 = (const float4*)(ea + (size_t)e * EDIM);
    const float4 a = e4[0], b = e4[1];
    uint4 u;
    u.x = (u32)f2bf(a.x) | ((u32)f2bf(a.y) << 16);
    u.y = (u32)f2bf(a.z) | ((u32)f2bf(a.w) << 16);
    u.z = (u32)f2bf(b.x) | ((u32)f2bf(b.y) << 16);
    u.w = (u32)f2bf(b.z) | ((u32)f2bf(b.w) << 16);
    eab16g[e] = u;
}

// ---- prep: swizzle 10 weight matrices into MFMA B-fragment order -----------
__global__ __launch_bounds__(256) void prep_w_kernel(
    const float* __restrict__ ligW1, const float* __restrict__ ligW2,
    const float* __restrict__ protW1, const float* __restrict__ protW2,
    const float* __restrict__ convW1, const float* __restrict__ convW2,
    u16* __restrict__ wf)
{
    const int id = blockIdx.x * 256 + threadIdx.x;
    if (id >= 10 * 4096) return;
    const int j = id & 7, l = (id >> 3) & 63, t = (id >> 9) & 3;
    const int c = (id >> 11) & 1, mat = id >> 12;
    const int k = c * 32 + ((l >> 4) * 8) + j;
    const int n = t * 16 + (l & 15);
    const float* src; int K = 64;
    if (mat == 0)      { src = ligW1;  K = IN_CH; }
    else if (mat == 1) { src = ligW2; }
    else if (mat == 2) { src = protW1; K = IN_CH; }
    else if (mat == 3) { src = protW2; }
    else {
        const int layer = (mat - 4) >> 1;
        src = (((mat - 4) & 1) ? convW2 : convW1) + (size_t)layer * H * H;
    }
    wf[id] = (k < K) ? f2bf(src[(size_t)k * H + n]) : (u16)0;
}

// ---- MFMA MLP over a gathered node list (encoder) --------------------------
__global__ __launch_bounds__(256) void enc_mfma_kernel(
    const int* __restrict__ list, const int* __restrict__ countPtr,
    const u16* __restrict__ xb,
    const u16* __restrict__ w1f, const u16* __restrict__ w2f,
    const float* __restrict__ bia1, const float* __restrict__ bia2,
    float* __restrict__ h, u16* __restrict__ h16)
{
    __shared__ __align__(16) u16 hid[4][16 * 72];
    const int wv = threadIdx.x >> 6;
    const int lane = threadIdx.x & 63;
    const int tile = blockIdx.x * 4 + wv;
    const int count = *countPtr;
    if (tile * 16 >= count) return;
    const int quad = lane >> 4;
    const int mi = lane & 15;
    int idx = tile * 16 + mi;
    if (idx >= count) idx = count - 1;
    const int nid = list[idx];

    const short8 a0 = *(const short8*)(xb + (size_t)nid * H + quad * 8);
    const short8 a1 = *(const short8*)(xb + (size_t)nid * H + 32 + quad * 8);

    floatx4 acc[4];
#pragma unroll
    for (int t = 0; t < 4; ++t) acc[t] = (floatx4){0.f, 0.f, 0.f, 0.f};
#pragma unroll
    for (int t = 0; t < 4; ++t) {
        const short8 b0 = *(const short8*)(w1f + ((size_t)(0 * 4 + t) * 64 + lane) * 8);
        const short8 b1 = *(const short8*)(w1f + ((size_t)(1 * 4 + t) * 64 + lane) * 8);
        acc[t] = mfma16(a0, b0, acc[t]);
        acc[t] = mfma16(a1, b1, acc[t]);
    }

    u16* myh = hid[wv];
#pragma unroll
    for (int t = 0; t < 4; ++t) {
        const float bv = bia1[t * 16 + mi];
#pragma unroll
        for (int r = 0; r < 4; ++r) {
            const float v = fmaxf(acc[t][r] + bv, 0.0f);
            myh[(quad * 4 + r) * 72 + t * 16 + mi] = f2bf(v);
        }
    }
    asm volatile("s_waitcnt lgkmcnt(0)" ::: "memory");

    const short8 c0 = *(const short8*)(myh + mi * 72 + quad * 8);
    const short8 c1 = *(const short8*)(myh + mi * 72 + 32 + quad * 8);

    floatx4 acc2[4];
#pragma unroll
    for (int t = 0; t < 4; ++t) acc2[t] = (floatx4){0.f, 0.f, 0.f, 0.f};
#pragma unroll
    for (int t = 0; t < 4; ++t) {
        const short8 b0 = *(const short8*)(w2f + ((size_t)(0 * 4 + t) * 64 + lane) * 8);
        const short8 b1 = *(const short8*)(w2f + ((size_t)(1 * 4 + t) * 64 + lane) * 8);
        acc2[t] = mfma16(c0, b0, acc2[t]);
        acc2[t] = mfma16(c1, b1, acc2[t]);
    }

#pragma unroll
    for (int t = 0; t < 4; ++t) {
        const float bv = bia2[t * 16 + mi];
#pragma unroll
        for (int r = 0; r < 4; ++r) {
            const int row = quad * 4 + r;
            const int nr = __shfl(nid, row, 64);
            if (tile * 16 + row < count) {
                const float v = fmaxf(acc2[t][r] + bv, 0.0f);
                h[(size_t)nr * H + t * 16 + mi] = v;
                h16[(size_t)nr * H + t * 16 + mi] = f2bf(v);
            }
        }
    }
}

// ---- MFMA MLP over consecutive nodes, in place (conv nn), no outer relu ----
__global__ __launch_bounds__(256) void mlp_mfma_kernel(
    const u16* __restrict__ w1f, const u16* __restrict__ w2f,
    const float* __restrict__ bia1, const float* __restrict__ bia2,
    float* __restrict__ h)
{
    __shared__ __align__(16) u16 hid[4][16 * 72];
    const int wv = threadIdx.x >> 6;
    const int lane = threadIdx.x & 63;
    const int tile = blockIdx.x * 4 + wv;
    if (tile >= NTILE) return;
    const int quad = lane >> 4;
    const int mi = lane & 15;
    const int row = tile * 16 + mi;
    const float* zr = h + (size_t)row * H;

    const float4 f0 = *(const float4*)(zr + quad * 8);
    const float4 f1 = *(const float4*)(zr + quad * 8 + 4);
    const float4 f2 = *(const float4*)(zr + 32 + quad * 8);
    const float4 f3 = *(const float4*)(zr + 32 + quad * 8 + 4);
    const short8 a0 = pack_bf8(f0, f1);
    const short8 a1 = pack_bf8(f2, f3);

    floatx4 acc[4];
#pragma unroll
    for (int t = 0; t < 4; ++t) acc[t] = (floatx4){0.f, 0.f, 0.f, 0.f};
#pragma unroll
    for (int t = 0; t < 4; ++t) {
        const short8 b0 = *(const short8*)(w1f + ((size_t)(0 * 4 + t) * 64 + lane) * 8);
        const short8 b1 = *(const short8*)(w1f + ((size_t)(1 * 4 + t) * 64 + lane) * 8);
        acc[t] = mfma16(a0, b0, acc[t]);
        acc[t] = mfma16(a1, b1, acc[t]);
    }

    u16* myh = hid[wv];
#pragma unroll
    for (int t = 0; t < 4; ++t) {
        const float bv = bia1[t * 16 + mi];
#pragma unroll
        for (int r = 0; r < 4; ++r) {
            const float v = fmaxf(acc[t][r] + bv, 0.0f);
            myh[(quad * 4 + r) * 72 + t * 16 + mi] = f2bf(v);
        }
    }
    asm volatile("s_waitcnt lgkmcnt(0)" ::: "memory");

    const short8 c0 = *(const short8*)(myh + mi * 72 + quad * 8);
    const short8 c1 = *(const short8*)(myh + mi * 72 + 32 + quad * 8);

    floatx4 acc2[4];
#pragma unroll
    for (int t = 0; t < 4; ++t) acc2[t] = (floatx4){0.f, 0.f, 0.f, 0.f};
#pragma unroll
    for (int t = 0; t < 4; ++t) {
        const short8 b0 = *(const short8*)(w2f + ((size_t)(0 * 4 + t) * 64 + lane) * 8);
        const short8 b1 = *(const short8*)(w2f + ((size_t)(1 * 4 + t) * 64 + lane) * 8);
        acc2[t] = mfma16(c0, b0, acc2[t]);
        acc2[t] = mfma16(c1, b1, acc2[t]);
    }

#pragma unroll
    for (int t = 0; t < 4; ++t) {
        const float bv = bia2[t * 16 + mi];
#pragma unroll
        for (int r = 0; r < 4; ++r) {
            const int orow = tile * 16 + quad * 4 + r;
            h[(size_t)orow * H + t * 16 + mi] = acc2[t][r] + bv;
        }
    }
}

// ---------------- per-graph node ranges (batch is sorted) -------------------
__global__ void bounds_kernel(const int* __restrict__ batch, int* __restrict__ start)
{
    int g = blockIdx.x * blockDim.x + threadIdx.x;
    if (g > GNUM) return;
    int lo = 0, hi = NN;
    while (lo < hi) {
        int mid = (lo + hi) >> 1;
        if (batch[mid] < g) lo = mid + 1; else hi = mid;
    }
    start[g] = lo;
}

// ---- coarse bucket histogram (LDS-local, then one flush per bucket) --------
__global__ __launch_bounds__(1024) void bhist_kernel(
    const int* __restrict__ ei, int* __restrict__ gbcount)
{
    __shared__ int cnt[NBK];
    const int t = threadIdx.x;
    if (t < NBK) cnt[t] = 0;
    __syncthreads();
    const int base = blockIdx.x * EPB_H;
#pragma unroll
    for (int v = 0; v < VPT_H; ++v) {
        const int e = base + v * 1024 + t;
        if (e < NE) atomicAdd(&cnt[ei[NE + e] >> BSH], 1);
    }
    __syncthreads();
    if (t < NBK && cnt[t]) atomicAdd(&gbcount[t], cnt[t]);
}

// ---- exclusive scan of 782 bucket counts -----------------------------------
__global__ __launch_bounds__(1024) void bscan_kernel(
    const int* __restrict__ gbcount, int* __restrict__ gstart, int* __restrict__ gcur)
{
    __shared__ int s[1024];
    const int t = threadIdx.x;
    int v = (t < NBK) ? gbcount[t] : 0;
    s[t] = v;
    __syncthreads();
#pragma unroll
    for (int off = 1; off < 1024; off <<= 1) {
        int tmp = (t >= off) ? s[t - off] : 0;
        __syncthreads();
        s[t] += tmp;
        __syncthreads();
    }
    if (t < NBK) { gstart[t] = s[t] - v; gcur[t] = s[t] - v; }
    if (t == 0) gstart[NBK] = NE;
}

// ---- coarse bucket partition, chunk-claimed (COALESCED-ish 8B writes) ------
// Record: .x = src | (dst&127)<<17, .y = eid. Per-block per-bucket records
// land contiguously (~21 x 8B runs) -> low write amplification (round-10's
// fully-scattered p1 hit 151.7MB WRITE_SIZE for 32MB of data).
__global__ __launch_bounds__(1024) void p1_kernel(
    const int* __restrict__ ei, int* __restrict__ gcur, int2* __restrict__ tmp)
{
    __shared__ int cnt[NBK];
    __shared__ int cur[NBK];
    const int t = threadIdx.x;
    if (t < NBK) cnt[t] = 0;
    __syncthreads();
    const int base = blockIdx.x * EPB_P1;
    int dstv[VPT_P1];
#pragma unroll
    for (int v = 0; v < VPT_P1; ++v) {
        const int e = base + v * 1024 + t;
        dstv[v] = -1;
        if (e < NE) {
            dstv[v] = ei[NE + e];
            atomicAdd(&cnt[dstv[v] >> BSH], 1);
        }
    }
    __syncthreads();
    if (t < NBK) cur[t] = cnt[t] ? atomicAdd(&gcur[t], cnt[t]) : 0;
    __syncthreads();
#pragma unroll
    for (int v = 0; v < VPT_P1; ++v) {
        const int e = base + v * 1024 + t;
        if (e < NE) {
            const int b = dstv[v] >> BSH;
            const int pos = atomicAdd(&cur[b], 1);
            tmp[pos] = make_int2(ei[e] | ((dstv[v] & (BDST - 1)) << 17), e);
        }
    }
}

// ---- ONE-PASS per-bucket counting sort (128 bins fit LDS trivially) --------
// Reads tmp 2x (hist + scatter) vs the old quarter-pass sort's 8x. Stages in
// LDS, flushes brec + gathered bfeat fully coalesced. Also emits astart[] at
// 8-dst granularity for aggr.
__global__ __launch_bounds__(1024) void sort1_kernel(
    const int2* __restrict__ tmp, const uint4* __restrict__ eab16g,
    const int* __restrict__ gstart,
    u32* __restrict__ brec, uint4* __restrict__ bfeat, int* __restrict__ astart)
{
    __shared__ int hist[BDST];
    __shared__ int cursor[BDST];
    __shared__ __align__(8) int2 stage[SCAP];
    const int b = blockIdx.x;
    const int t = threadIdx.x;
    const int s = gstart[b], e = gstart[b + 1];
    const int cnt = e - s;

    if (t < BDST) hist[t] = 0;
    __syncthreads();
    for (int i = s + t; i < e; i += 1024)
        atomicAdd(&hist[(tmp[i].x >> 17) & (BDST - 1)], 1);
    __syncthreads();
    if (t < BDST) cursor[t] = hist[t];
    __syncthreads();
#pragma unroll
    for (int off = 1; off < BDST; off <<= 1) {
        int v = (t < BDST && t >= off) ? cursor[t - off] : 0;
        __syncthreads();
        if (t < BDST) cursor[t] += v;   // inclusive
        __syncthreads();
    }
    if (t < BDST) cursor[t] -= hist[t]; // exclusive
    __syncthreads();
    if (t < GRP) {
        const int a = b * GRP + t;
        if (a < NAGG) astart[a] = s + cursor[t * BDST2];
    }
    if (b == 0 && t == 0) astart[NAGG] = NE;

    if (cnt <= SCAP) {
        for (int i = s + t; i < e; i += 1024) {
            const int2 r = tmp[i];
            const int slot = atomicAdd(&cursor[(r.x >> 17) & (BDST - 1)], 1);
            stage[slot] = r;
        }
        __syncthreads();
        for (int i = t; i < cnt; i += 1024) {
            const int2 r = stage[i];
            brec[s + i] = (u32)r.x;
            bfeat[s + i] = eab16g[r.y];   // random read (L3), coalesced write
        }
    } else {
        // fallback: direct global scatter (should never happen)
        if (t < BDST) cursor[t] += s;
        __syncthreads();
        for (int i = s + t; i < e; i += 1024) {
            const int2 r = tmp[i];
            const int pos = atomicAdd(&cursor[(r.x >> 17) & (BDST - 1)], 1);
            brec[pos] = (u32)r.x;
            bfeat[pos] = eab16g[r.y];
        }
    }
}

// ---- edge aggregation: one WAVE per 8-dst group over SORTED edges ----------
// Single-register run-accumulate (proven inner loop), zero atomics hot path.
__global__ __launch_bounds__(256, 4) void aggr_kernel(
    const u32* __restrict__ brec,
    const u32* __restrict__ bfeat32,
    const int* __restrict__ astart,
    const float* __restrict__ We, const float* __restrict__ be,
    const u16* __restrict__ h16, float* __restrict__ h)
{
    const int lane = threadIdx.x & 63;
    const int bk = blockIdx.x * 4 + (threadIdx.x >> 6);   // 8-dst group = wave
    const int row0 = bk * BDST2;
    const int s = astart[bk], e = astart[bk + 1];
    if (s >= e) return;

    float we_r[EDIM];
#pragma unroll
    for (int d = 0; d < EDIM; ++d) we_r[d] = We[d * H + lane];
    const float be_r = be[lane];

    float acc = 0.0f;
    int cur = -1;

    for (int base = s; base < e; base += EPW) {
        const int cnt = min(EPW, e - base);     // wave-uniform
        u32 rec = 0;
        if ((lane & 15) < cnt) rec = brec[base + (lane & 15)];
        u32 eu = 0;
        if (lane < cnt * 4) eu = bfeat32[(size_t)base * 4 + lane];

        float hv[EPW];
#pragma unroll
        for (int j = 0; j < EPW; ++j) {
            const int sj = (int)(__builtin_amdgcn_readlane(rec, j) & 0x1ffffu);
            hv[j] = bf2f(h16[(size_t)sj * H + lane]);   // rec=0 for tail -> safe
        }
#pragma unroll
        for (int j = 0; j < EPW; ++j) {
            if (j < cnt) {                      // wave-uniform
                const u32 rj = __builtin_amdgcn_readlane(rec, j);
                const int ld = (int)((rj >> 17) & (BDST2 - 1));
                float msg = be_r;
#pragma unroll
                for (int p = 0; p < 4; ++p) {
                    const u32 w2 = __builtin_amdgcn_readlane(eu, j * 4 + p);
                    msg = fmaf(__uint_as_float(w2 << 16), we_r[2 * p], msg);
                    msg = fmaf(__uint_as_float(w2 & 0xffff0000u), we_r[2 * p + 1], msg);
                }
                const float val = fmaxf(hv[j] + msg, 0.0f);
                if (ld != cur) {                // wave-uniform, rare (runs ~16)
                    if (cur >= 0)
                        unsafeAtomicAdd(&h[(size_t)(row0 + cur) * H + lane], acc);
                    acc = 0.0f;
                    cur = ld;
                }
                acc += val;
            }
        }
    }
    unsafeAtomicAdd(&h[(size_t)(row0 + cur) * H + lane], acc);
}

// ------- GraphNorm + relu, in place; refresh h16; optional pool accum -------
__global__ __launch_bounds__(1024) void graphnorm_kernel(
    float* __restrict__ h, u16* __restrict__ h16,
    const int* __restrict__ start,
    const float* __restrict__ w, const float* __restrict__ b,
    const float* __restrict__ a,
    float* __restrict__ pool, int do_pool)
{
    __shared__ float red1[16][H], red2[16][H];
    __shared__ float amean_s[H], rstd_s[H];
    const int g = blockIdx.x;
    const int lane = threadIdx.x & 63;
    const int wv = threadIdx.x >> 6;
    const int s = start[g], e = start[g + 1];

    float s1 = 0.f, s2 = 0.f;
    for (int i = s + wv; i < e; i += 16) {
        float v = h[(size_t)i * H + lane];
        s1 += v; s2 += v * v;
    }
    red1[wv][lane] = s1; red2[wv][lane] = s2;
    __syncthreads();
    if (threadIdx.x < H) {
        float t1 = 0.f, t2 = 0.f;
#pragma unroll
        for (int k = 0; k < 16; ++k) { t1 += red1[k][lane]; t2 += red2[k][lane]; }
        float cnt = fmaxf((float)(e - s), 1.0f);
        float mean = t1 / cnt;
        float alpha = a[lane];
        float var = t2 / cnt - (2.0f * alpha - alpha * alpha) * mean * mean;
        var = fmaxf(var, 0.0f);
        amean_s[lane] = alpha * mean;
        rstd_s[lane] = rsqrtf(var + EPSV);
    }
    __syncthreads();
    const float am = amean_s[lane], rstd = rstd_s[lane];
    const float ww = w[lane], bb = b[lane];
    float ps = 0.f;
    for (int i = s + wv; i < e; i += 16) {
        float v = (h[(size_t)i * H + lane] - am) * rstd * ww + bb;
        v = fmaxf(v, 0.0f);
        h[(size_t)i * H + lane] = v;
        h16[(size_t)i * H + lane] = f2bf(v);
        ps += v;
    }
    if (do_pool && e > s) unsafeAtomicAdd(&pool[g * H + lane], ps);
}

// ---------------- readout from pooled sums ----------------------------------
__global__ __launch_bounds__(64) void final_kernel(
    const float* __restrict__ pool,
    const float* __restrict__ W1, const float* __restrict__ b1,
    const float* __restrict__ W2, const float* __restrict__ b2,
    float* __restrict__ out)
{
    const int g = blockIdx.x;
    const int lane = threadIdx.x;
    const float gv = pool[g * H + lane];
    float acc = b1[lane];
#pragma unroll
    for (int d = 0; d < H; ++d)
        acc = fmaf(__shfl(gv, d, 64), W1[d * H + lane], acc);
    float r = fmaxf(acc, 0.0f);
    float v = r * W2[lane];
#pragma unroll
    for (int o = 32; o > 0; o >>= 1) v += __shfl_xor(v, o, 64);
    if (lane == 0) out[g] = v + b2[0];
}

extern "C" void kernel_launch(void* const* d_in, const int* in_sizes, int n_in,
                              void* d_out, int out_size, void* d_ws, size_t ws_size,
                              hipStream_t stream)
{
    const float* x      = (const float*)d_in[0];
    const int*   ei     = (const int*)  d_in[1];
    const float* ea     = (const float*)d_in[2];
    const int*   batch  = (const int*)  d_in[3];
    const float* ligW1  = (const float*)d_in[4];
    const float* ligb1  = (const float*)d_in[5];
    const float* ligW2  = (const float*)d_in[6];
    const float* ligb2  = (const float*)d_in[7];
    const float* protW1 = (const float*)d_in[8];
    const float* protb1 = (const float*)d_in[9];
    const float* protW2 = (const float*)d_in[10];
    const float* protb2 = (const float*)d_in[11];
    const float* convWe = (const float*)d_in[12];
    const float* convbe = (const float*)d_in[13];
    const float* convW1 = (const float*)d_in[14];
    const float* convb1 = (const float*)d_in[15];
    const float* convW2 = (const float*)d_in[16];
    const float* convb2 = (const float*)d_in[17];
    const float* normw  = (const float*)d_in[18];
    const float* normb  = (const float*)d_in[19];
    const float* norma  = (const float*)d_in[20];
    const float* outW1  = (const float*)d_in[21];
    const float* outb1  = (const float*)d_in[22];
    const float* outW2  = (const float*)d_in[23];
    const float* outb2  = (const float*)d_in[24];

    float* out = (float*)d_out;

    // -------- workspace layout (16B-aligned blocks first) -------------------
    float* h         = (float*)d_ws;                    // NN*H f32      25.6 MB
    uint4* bfeat     = (uint4*)(h + (size_t)NN * H);    // NE uint4      25.6 MB
    u32*   brec      = (u32*)(bfeat + (size_t)NE);      // NE u32         6.4 MB
    u16*   h16       = (u16*)(brec + (size_t)NE);       // NN*H u16      12.8 MB
    u16*   xb        = h16 + (size_t)NN * H;            // NN*H u16      12.8 MB
    u16*   wf        = xb + (size_t)NN * H;             // 40960 u16     80 KB
    int2*  tmp       = (int2*)h;                        // NE int2 (overlay h)
    uint4* eab16g    = (uint4*)h16;                     // NE uint4 (overlay h16+xb)

    int*   ctr       = (int*)(wf + 40960);              // 2     (zeroed)
    int*   gbcount   = ctr + 2;                         // NBK   (zeroed)
    float* pool      = (float*)(gbcount + NBK);         // GNUM*H (zeroed)
    int*   gstart    = (int*)(pool + GNUM * H);         // NBK+1
    int*   gcur      = gstart + (NBK + 1);              // NBK
    int*   astart    = gcur + NBK;                      // NAGG+1
    int*   start     = astart + (NAGG + 1);             // GNUM+1
    int*   lig_list  = start + (GNUM + 1);              // NN
    int*   prot_list = lig_list + NN;                   // NN

    hipMemsetAsync(ctr, 0, ((size_t)2 + NBK + GNUM * H) * sizeof(int), stream);

    // ---- prep not touching overlays ----
    prep_w_kernel<<<(10 * 4096 + 255) / 256, 256, 0, stream>>>(
        ligW1, ligW2, protW1, protW2, convW1, convW2, wf);
    partition_kernel<<<(NN + 255) / 256, 256, 0, stream>>>(x, ctr, lig_list, prot_list);
    bounds_kernel<<<2, 256, 0, stream>>>(batch, start);

    // ---- build: coarse hist -> scan -> ea conv -> partition -> 1-pass sort -
    bhist_kernel<<<NBLK_H, 1024, 0, stream>>>(ei, gbcount);
    bscan_kernel<<<1, 1024, 0, stream>>>(gbcount, gstart, gcur);
    ea2b_kernel<<<(NE + 255) / 256, 256, 0, stream>>>(ea, eab16g);
    p1_kernel<<<NBLK_P1, 1024, 0, stream>>>(ei, gcur, tmp);
    sort1_kernel<<<NBK, 1024, 0, stream>>>(tmp, eab16g, gstart, brec, bfeat, astart);

    // ---- xb after eab16g overlay is dead; then encoder (h after tmp dead) --
    xb_kernel<<<(NN * H + 255) / 256, 256, 0, stream>>>(x, xb);
    const int enc_blocks = (NTILE + 3) / 4;
    enc_mfma_kernel<<<enc_blocks, 256, 0, stream>>>(
        lig_list, &ctr[0], xb, wf + 0 * 4096, wf + 1 * 4096, ligb1, ligb2, h, h16);
    enc_mfma_kernel<<<enc_blocks, 256, 0, stream>>>(
        prot_list, &ctr[1], xb, wf + 2 * 4096, wf + 3 * 4096, protb1, protb2, h, h16);

    const int aggr_blocks = NAGG / 4;   // 3125, exact (one wave per 8-dst group)
    const int mlp_blocks = (NTILE + 3) / 4;
    for (int l = 0; l < 3; ++l) {
        aggr_kernel<<<aggr_blocks, 256, 0, stream>>>(
            brec, (const u32*)bfeat, astart,
            convWe + (size_t)l * EDIM * H, convbe + (size_t)l * H, h16, h);
        mlp_mfma_kernel<<<mlp_blocks, 256, 0, stream>>>(
            wf + (size_t)(4 + 2 * l) * 4096, wf + (size_t)(5 + 2 * l) * 4096,
            convb1 + (size_t)l * H, convb2 + (size_t)l * H, h);
        graphnorm_kernel<<<GNUM, 1024, 0, stream>>>(
            h, h16, start, normw + (size_t)l * H, normb + (size_t)l * H,
            norma + (size_t)l * H, pool, (l == 2) ? 1 : 0);
    }
    final_kernel<<<GNUM, 64, 0, stream>>>(pool, outW1, outb1, outW2, outb2, out);
}

// Round 13
// 603.298 us; speedup vs baseline: 1.2206x; 1.0531x over previous
//
#include <hip/hip_runtime.h>

#define NN 100000   // nodes
#define NE 1600000  // edges
#define IN_CH 41
#define EDIM 8
#define H 64
#define GNUM 256
#define ATOM 21
#define EPSV 1e-5f
#define EPW 16      // edges per wave-chunk in aggr
#define NTILE (NN / 16)   // 6250 node tiles (exact)

#define BSH 7       // coarse bucket shift: dst>>7, 128 dst per bucket
#define BDST 128    // dst per coarse bucket
#define NBK 782     // ceil(NN / 128)
#define GRP 16      // 8-dst groups per coarse bucket (128/8)
#define BDST2 8     // dst rows per aggr wave (exclusive ownership)
#define NAGG 12500  // NN / 8, exact (aggr buckets)
#define SCAP 3584   // sort stage capacity (mean 2046, +34 sigma)

#define VPT_H 8
#define EPB_H (1024 * VPT_H)               // 8192 edges/block (bhist)
#define NBLK_H ((NE + EPB_H - 1) / EPB_H)  // 196
#define VPT_P1 16
#define EPB_P1 (1024 * VPT_P1)             // 16384 edges/block (p1)
#define NBLK_P1 ((NE + EPB_P1 - 1) / EPB_P1)  // 98

typedef unsigned short u16;
typedef unsigned int u32;
typedef unsigned long long u64;
typedef __attribute__((ext_vector_type(8))) short short8;
typedef __attribute__((ext_vector_type(4))) float floatx4;

__device__ __forceinline__ u16 f2bf(float f) {
    u32 u = __float_as_uint(f);
    u32 r = (u + 0x7FFFu + ((u >> 16) & 1u)) >> 16;   // RNE
    return (u16)r;
}
__device__ __forceinline__ float bf2f(u16 u) {
    return __uint_as_float(((u32)u) << 16);
}
__device__ __forceinline__ floatx4 mfma16(short8 a, short8 b, floatx4 c) {
    return __builtin_amdgcn_mfma_f32_16x16x32_bf16(a, b, c, 0, 0, 0);
}
__device__ __forceinline__ short8 pack_bf8(float4 a, float4 b) {
    short8 s;
    s[0] = (short)f2bf(a.x); s[1] = (short)f2bf(a.y);
    s[2] = (short)f2bf(a.z); s[3] = (short)f2bf(a.w);
    s[4] = (short)f2bf(b.x); s[5] = (short)f2bf(b.y);
    s[6] = (short)f2bf(b.z); s[7] = (short)f2bf(b.w);
    return s;
}
// pack one ea row (8 f32) to bf16x8 as uint4
__device__ __forceinline__ uint4 pack_ea(const float* __restrict__ ea, int eid) {
    const float4* e4 = (const float4*)(ea + (size_t)eid * EDIM);
    const float4 a = e4[0], b = e4[1];
    uint4 u;
    u.x = (u32)f2bf(a.x) | ((u32)f2bf(a.y) << 16);
    u.y = (u32)f2bf(a.z) | ((u32)f2bf(a.w) << 16);
    u.z = (u32)f2bf(b.x) | ((u32)f2bf(b.y) << 16);
    u.w = (u32)f2bf(b.z) | ((u32)f2bf(b.w) << 16);
    return u;
}

// ---- partition: mask per node -> lig_list / prot_list ----------------------
__global__ __launch_bounds__(256) void partition_kernel(
    const float* __restrict__ x, int* __restrict__ ctr,
    int* __restrict__ lig_list, int* __restrict__ prot_list)
{
    const int n = blockIdx.x * 256 + threadIdx.x;
    const int lane = threadIdx.x & 63;
    float m = 0.0f;
    if (n < NN) {
        const float* xr = x + (size_t)n * IN_CH + ATOM;
#pragma unroll
        for (int d = 0; d < IN_CH - ATOM; ++d) m += fabsf(xr[d]);
    }
    const bool valid = n < NN;
    const bool prot = valid && (m > 1e-6f);
    const bool lig = valid && !prot;

    const u64 bl = __ballot(lig);
    const u64 bp = __ballot(prot);
    const u64 below_m = (lane == 63) ? (~0ull >> 1) : ((1ull << lane) - 1ull);
    int base_l = 0, base_p = 0;
    if (lane == 0) {
        if (bl) base_l = atomicAdd(&ctr[0], (int)__popcll(bl));
        if (bp) base_p = atomicAdd(&ctr[1], (int)__popcll(bp));
    }
    base_l = __shfl(base_l, 0, 64);
    base_p = __shfl(base_p, 0, 64);
    if (lig)  lig_list [base_l + (int)__popcll(bl & below_m)] = n;
    if (prot) prot_list[base_p + (int)__popcll(bp & below_m)] = n;
}

// ---- xb: zero-padded bf16 copy of x [NN x 64] ------------------------------
__global__ __launch_bounds__(256) void xb_kernel(
    const float* __restrict__ x, u16* __restrict__ xb)
{
    const int id = blockIdx.x * 256 + threadIdx.x;
    if (id >= NN * H) return;
    const int n = id >> 6, d = id & 63;
    xb[id] = (d < IN_CH) ? f2bf(x[(size_t)n * IN_CH + d]) : (u16)0;
}

// ---- prep: swizzle 10 weight matrices into MFMA B-fragment order -----------
__global__ __launch_bounds__(256) void prep_w_kernel(
    const float* __restrict__ ligW1, const float* __restrict__ ligW2,
    const float* __restrict__ protW1, const float* __restrict__ protW2,
    const float* __restrict__ convW1, const float* __restrict__ convW2,
    u16* __restrict__ wf)
{
    const int id = blockIdx.x * 256 + threadIdx.x;
    if (id >= 10 * 4096) return;
    const int j = id & 7, l = (id >> 3) & 63, t = (id >> 9) & 3;
    const int c = (id >> 11) & 1, mat = id >> 12;
    const int k = c * 32 + ((l >> 4) * 8) + j;
    const int n = t * 16 + (l & 15);
    const float* src; int K = 64;
    if (mat == 0)      { src = ligW1;  K = IN_CH; }
    else if (mat == 1) { src = ligW2; }
    else if (mat == 2) { src = protW1; K = IN_CH; }
    else if (mat == 3) { src = protW2; }
    else {
        const int layer = (mat - 4) >> 1;
        src = (((mat - 4) & 1) ? convW2 : convW1) + (size_t)layer * H * H;
    }
    wf[id] = (k < K) ? f2bf(src[(size_t)k * H + n]) : (u16)0;
}

// ---- MFMA MLP over a gathered node list (encoder) --------------------------
__global__ __launch_bounds__(256) void enc_mfma_kernel(
    const int* __restrict__ list, const int* __restrict__ countPtr,
    const u16* __restrict__ xb,
    const u16* __restrict__ w1f, const u16* __restrict__ w2f,
    const float* __restrict__ bia1, const float* __restrict__ bia2,
    float* __restrict__ h, u16* __restrict__ h16)
{
    __shared__ __align__(16) u16 hid[4][16 * 72];
    const int wv = threadIdx.x >> 6;
    const int lane = threadIdx.x & 63;
    const int tile = blockIdx.x * 4 + wv;
    const int count = *countPtr;
    if (tile * 16 >= count) return;
    const int quad = lane >> 4;
    const int mi = lane & 15;
    int idx = tile * 16 + mi;
    if (idx >= count) idx = count - 1;
    const int nid = list[idx];

    const short8 a0 = *(const short8*)(xb + (size_t)nid * H + quad * 8);
    const short8 a1 = *(const short8*)(xb + (size_t)nid * H + 32 + quad * 8);

    floatx4 acc[4];
#pragma unroll
    for (int t = 0; t < 4; ++t) acc[t] = (floatx4){0.f, 0.f, 0.f, 0.f};
#pragma unroll
    for (int t = 0; t < 4; ++t) {
        const short8 b0 = *(const short8*)(w1f + ((size_t)(0 * 4 + t) * 64 + lane) * 8);
        const short8 b1 = *(const short8*)(w1f + ((size_t)(1 * 4 + t) * 64 + lane) * 8);
        acc[t] = mfma16(a0, b0, acc[t]);
        acc[t] = mfma16(a1, b1, acc[t]);
    }

    u16* myh = hid[wv];
#pragma unroll
    for (int t = 0; t < 4; ++t) {
        const float bv = bia1[t * 16 + mi];
#pragma unroll
        for (int r = 0; r < 4; ++r) {
            const float v = fmaxf(acc[t][r] + bv, 0.0f);
            myh[(quad * 4 + r) * 72 + t * 16 + mi] = f2bf(v);
        }
    }
    asm volatile("s_waitcnt lgkmcnt(0)" ::: "memory");

    const short8 c0 = *(const short8*)(myh + mi * 72 + quad * 8);
    const short8 c1 = *(const short8*)(myh + mi * 72 + 32 + quad * 8);

    floatx4 acc2[4];
#pragma unroll
    for (int t = 0; t < 4; ++t) acc2[t] = (floatx4){0.f, 0.f, 0.f, 0.f};
#pragma unroll
    for (int t = 0; t < 4; ++t) {
        const short8 b0 = *(const short8*)(w2f + ((size_t)(0 * 4 + t) * 64 + lane) * 8);
        const short8 b1 = *(const short8*)(w2f + ((size_t)(1 * 4 + t) * 64 + lane) * 8);
        acc2[t] = mfma16(c0, b0, acc2[t]);
        acc2[t] = mfma16(c1, b1, acc2[t]);
    }

#pragma unroll
    for (int t = 0; t < 4; ++t) {
        const float bv = bia2[t * 16 + mi];
#pragma unroll
        for (int r = 0; r < 4; ++r) {
            const int row = quad * 4 + r;
            const int nr = __shfl(nid, row, 64);
            if (tile * 16 + row < count) {
                const float v = fmaxf(acc2[t][r] + bv, 0.0f);
                h[(size_t)nr * H + t * 16 + mi] = v;
                h16[(size_t)nr * H + t * 16 + mi] = f2bf(v);
            }
        }
    }
}

// ---- MFMA MLP over consecutive nodes, in place (conv nn), no outer relu ----
__global__ __launch_bounds__(256) void mlp_mfma_kernel(
    const u16* __restrict__ w1f, const u16* __restrict__ w2f,
    const float* __restrict__ bia1, const float* __restrict__ bia2,
    float* __restrict__ h)
{
    __shared__ __align__(16) u16 hid[4][16 * 72];
    const int wv = threadIdx.x >> 6;
    const int lane = threadIdx.x & 63;
    const int tile = blockIdx.x * 4 + wv;
    if (tile >= NTILE) return;
    const int quad = lane >> 4;
    const int mi = lane & 15;
    const int row = tile * 16 + mi;
    const float* zr = h + (size_t)row * H;

    const float4 f0 = *(const float4*)(zr + quad * 8);
    const float4 f1 = *(const float4*)(zr + quad * 8 + 4);
    const float4 f2 = *(const float4*)(zr + 32 + quad * 8);
    const float4 f3 = *(const float4*)(zr + 32 + quad * 8 + 4);
    const short8 a0 = pack_bf8(f0, f1);
    const short8 a1 = pack_bf8(f2, f3);

    floatx4 acc[4];
#pragma unroll
    for (int t = 0; t < 4; ++t) acc[t] = (floatx4){0.f, 0.f, 0.f, 0.f};
#pragma unroll
    for (int t = 0; t < 4; ++t) {
        const short8 b0 = *(const short8*)(w1f + ((size_t)(0 * 4 + t) * 64 + lane) * 8);
        const short8 b1 = *(const short8*)(w1f + ((size_t)(1 * 4 + t) * 64 + lane) * 8);
        acc[t] = mfma16(a0, b0, acc[t]);
        acc[t] = mfma16(a1, b1, acc[t]);
    }

    u16* myh = hid[wv];
#pragma unroll
    for (int t = 0; t < 4; ++t) {
        const float bv = bia1[t * 16 + mi];
#pragma unroll
        for (int r = 0; r < 4; ++r) {
            const float v = fmaxf(acc[t][r] + bv, 0.0f);
            myh[(quad * 4 + r) * 72 + t * 16 + mi] = f2bf(v);
        }
    }
    asm volatile("s_waitcnt lgkmcnt(0)" ::: "memory");

    const short8 c0 = *(const short8*)(myh + mi * 72 + quad * 8);
    const short8 c1 = *(const short8*)(myh + mi * 72 + 32 + quad * 8);

    floatx4 acc2[4];
#pragma unroll
    for (int t = 0; t < 4; ++t) acc2[t] = (floatx4){0.f, 0.f, 0.f, 0.f};
#pragma unroll
    for (int t = 0; t < 4; ++t) {
        const short8 b0 = *(const short8*)(w2f + ((size_t)(0 * 4 + t) * 64 + lane) * 8);
        const short8 b1 = *(const short8*)(w2f + ((size_t)(1 * 4 + t) * 64 + lane) * 8);
        acc2[t] = mfma16(c0, b0, acc2[t]);
        acc2[t] = mfma16(c1, b1, acc2[t]);
    }

#pragma unroll
    for (int t = 0; t < 4; ++t) {
        const float bv = bia2[t * 16 + mi];
#pragma unroll
        for (int r = 0; r < 4; ++r) {
            const int orow = tile * 16 + quad * 4 + r;
            h[(size_t)orow * H + t * 16 + mi] = acc2[t][r] + bv;
        }
    }
}

// ---------------- per-graph node ranges (batch is sorted) -------------------
__global__ void bounds_kernel(const int* __restrict__ batch, int* __restrict__ start)
{
    int g = blockIdx.x * blockDim.x + threadIdx.x;
    if (g > GNUM) return;
    int lo = 0, hi = NN;
    while (lo < hi) {
        int mid = (lo + hi) >> 1;
        if (batch[mid] < g) lo = mid + 1; else hi = mid;
    }
    start[g] = lo;
}

// ---- coarse bucket histogram (LDS-local, then one flush per bucket) --------
__global__ __launch_bounds__(1024) void bhist_kernel(
    const int* __restrict__ ei, int* __restrict__ gbcount)
{
    __shared__ int cnt[NBK];
    const int t = threadIdx.x;
    if (t < NBK) cnt[t] = 0;
    __syncthreads();
    const int base = blockIdx.x * EPB_H;
#pragma unroll
    for (int v = 0; v < VPT_H; ++v) {
        const int e = base + v * 1024 + t;
        if (e < NE) atomicAdd(&cnt[ei[NE + e] >> BSH], 1);
    }
    __syncthreads();
    if (t < NBK && cnt[t]) atomicAdd(&gbcount[t], cnt[t]);
}

// ---- exclusive scan of 782 bucket counts -----------------------------------
__global__ __launch_bounds__(1024) void bscan_kernel(
    const int* __restrict__ gbcount, int* __restrict__ gstart, int* __restrict__ gcur)
{
    __shared__ int s[1024];
    const int t = threadIdx.x;
    int v = (t < NBK) ? gbcount[t] : 0;
    s[t] = v;
    __syncthreads();
#pragma unroll
    for (int off = 1; off < 1024; off <<= 1) {
        int tmp = (t >= off) ? s[t - off] : 0;
        __syncthreads();
        s[t] += tmp;
        __syncthreads();
    }
    if (t < NBK) { gstart[t] = s[t] - v; gcur[t] = s[t] - v; }
    if (t == 0) gstart[NBK] = NE;
}

// ---- coarse bucket partition, chunk-claimed (COALESCED-ish 8B writes) ------
// Record: .x = src | (dst&127)<<17, .y = eid.
__global__ __launch_bounds__(1024) void p1_kernel(
    const int* __restrict__ ei, int* __restrict__ gcur, int2* __restrict__ tmp)
{
    __shared__ int cnt[NBK];
    __shared__ int cur[NBK];
    const int t = threadIdx.x;
    if (t < NBK) cnt[t] = 0;
    __syncthreads();
    const int base = blockIdx.x * EPB_P1;
    int dstv[VPT_P1];
#pragma unroll
    for (int v = 0; v < VPT_P1; ++v) {
        const int e = base + v * 1024 + t;
        dstv[v] = -1;
        if (e < NE) {
            dstv[v] = ei[NE + e];
            atomicAdd(&cnt[dstv[v] >> BSH], 1);
        }
    }
    __syncthreads();
    if (t < NBK) cur[t] = cnt[t] ? atomicAdd(&gcur[t], cnt[t]) : 0;
    __syncthreads();
#pragma unroll
    for (int v = 0; v < VPT_P1; ++v) {
        const int e = base + v * 1024 + t;
        if (e < NE) {
            const int b = dstv[v] >> BSH;
            const int pos = atomicAdd(&cur[b], 1);
            tmp[pos] = make_int2(ei[e] | ((dstv[v] & (BDST - 1)) << 17), e);
        }
    }
}

// ---- ONE-PASS per-bucket counting sort; gathers ea DIRECTLY (no ea2b) ------
__global__ __launch_bounds__(1024) void sort1_kernel(
    const int2* __restrict__ tmp, const float* __restrict__ ea,
    const int* __restrict__ gstart,
    u32* __restrict__ brec, uint4* __restrict__ bfeat, int* __restrict__ astart)
{
    __shared__ int hist[BDST];
    __shared__ int cursor[BDST];
    __shared__ __align__(8) int2 stage[SCAP];
    const int b = blockIdx.x;
    const int t = threadIdx.x;
    const int s = gstart[b], e = gstart[b + 1];
    const int cnt = e - s;

    if (t < BDST) hist[t] = 0;
    __syncthreads();
    for (int i = s + t; i < e; i += 1024)
        atomicAdd(&hist[(tmp[i].x >> 17) & (BDST - 1)], 1);
    __syncthreads();
    if (t < BDST) cursor[t] = hist[t];
    __syncthreads();
#pragma unroll
    for (int off = 1; off < BDST; off <<= 1) {
        int v = (t < BDST && t >= off) ? cursor[t - off] : 0;
        __syncthreads();
        if (t < BDST) cursor[t] += v;   // inclusive
        __syncthreads();
    }
    if (t < BDST) cursor[t] -= hist[t]; // exclusive
    __syncthreads();
    if (t < GRP) {
        const int a = b * GRP + t;
        if (a < NAGG) astart[a] = s + cursor[t * BDST2];
    }
    if (b == 0 && t == 0) astart[NAGG] = NE;

    if (cnt <= SCAP) {
        for (int i = s + t; i < e; i += 1024) {
            const int2 r = tmp[i];
            const int slot = atomicAdd(&cursor[(r.x >> 17) & (BDST - 1)], 1);
            stage[slot] = r;
        }
        __syncthreads();
        for (int i = t; i < cnt; i += 1024) {
            const int2 r = stage[i];
            brec[s + i] = (u32)r.x;
            bfeat[s + i] = pack_ea(ea, r.y);   // random read (L3), coalesced write
        }
    } else {
        // fallback: direct global scatter (should never happen)
        if (t < BDST) cursor[t] += s;
        __syncthreads();
        for (int i = s + t; i < e; i += 1024) {
            const int2 r = tmp[i];
            const int pos = atomicAdd(&cursor[(r.x >> 17) & (BDST - 1)], 1);
            brec[pos] = (u32)r.x;
            bfeat[pos] = pack_ea(ea, r.y);
        }
    }
}

// ---- edge aggregation: one WAVE per 8-dst group over SORTED edges ----------
// Single-register run-accumulate. Main loop has NO per-j guards (full chunks
// of EPW); a single guarded tail chunk handles the remainder.
__global__ __launch_bounds__(256) void aggr_kernel(
    const u32* __restrict__ brec,
    const u32* __restrict__ bfeat32,
    const int* __restrict__ astart,
    const float* __restrict__ We, const float* __restrict__ be,
    const u16* __restrict__ h16, float* __restrict__ h)
{
    const int lane = threadIdx.x & 63;
    const int bk = blockIdx.x * 4 + (threadIdx.x >> 6);   // 8-dst group = wave
    const int row0 = bk * BDST2;
    const int s = astart[bk], e = astart[bk + 1];
    if (s >= e) return;

    float we_r[EDIM];
#pragma unroll
    for (int d = 0; d < EDIM; ++d) we_r[d] = We[d * H + lane];
    const float be_r = be[lane];

    float acc = 0.0f;
    int cur = -1;

    const int nfull = (e - s) / EPW;
    int base = s;
    for (int c = 0; c < nfull; ++c, base += EPW) {
        const u32 rec = brec[base + (lane & 15)];
        const u32 eu = bfeat32[(size_t)base * 4 + lane];

        float hv[EPW];
#pragma unroll
        for (int j = 0; j < EPW; ++j) {
            const int sj = (int)(__builtin_amdgcn_readlane(rec, j) & 0x1ffffu);
            hv[j] = bf2f(h16[(size_t)sj * H + lane]);
        }
#pragma unroll
        for (int j = 0; j < EPW; ++j) {
            const u32 rj = __builtin_amdgcn_readlane(rec, j);
            const int ld = (int)((rj >> 17) & (BDST2 - 1));
            float msg = be_r;
#pragma unroll
            for (int p = 0; p < 4; ++p) {
                const u32 w2 = __builtin_amdgcn_readlane(eu, j * 4 + p);
                msg = fmaf(__uint_as_float(w2 << 16), we_r[2 * p], msg);
                msg = fmaf(__uint_as_float(w2 & 0xffff0000u), we_r[2 * p + 1], msg);
            }
            const float val = fmaxf(hv[j] + msg, 0.0f);
            if (ld != cur) {                // wave-uniform, rare (runs ~16)
                if (cur >= 0)
                    unsafeAtomicAdd(&h[(size_t)(row0 + cur) * H + lane], acc);
                acc = 0.0f;
                cur = ld;
            }
            acc += val;
        }
    }
    // guarded tail chunk
    if (base < e) {
        const int cnt = e - base;
        u32 rec = 0;
        if ((lane & 15) < cnt) rec = brec[base + (lane & 15)];
        u32 eu = 0;
        if (lane < cnt * 4) eu = bfeat32[(size_t)base * 4 + lane];

        float hv[EPW];
#pragma unroll
        for (int j = 0; j < EPW; ++j) {
            const int sj = (int)(__builtin_amdgcn_readlane(rec, j) & 0x1ffffu);
            hv[j] = bf2f(h16[(size_t)sj * H + lane]);   // rec=0 for tail -> safe
        }
#pragma unroll
        for (int j = 0; j < EPW; ++j) {
            if (j < cnt) {
                const u32 rj = __builtin_amdgcn_readlane(rec, j);
                const int ld = (int)((rj >> 17) & (BDST2 - 1));
                float msg = be_r;
#pragma unroll
                for (int p = 0; p < 4; ++p) {
                    const u32 w2 = __builtin_amdgcn_readlane(eu, j * 4 + p);
                    msg = fmaf(__uint_as_float(w2 << 16), we_r[2 * p], msg);
                    msg = fmaf(__uint_as_float(w2 & 0xffff0000u), we_r[2 * p + 1], msg);
                }
                const float val = fmaxf(hv[j] + msg, 0.0f);
                if (ld != cur) {
                    if (cur >= 0)
                        unsafeAtomicAdd(&h[(size_t)(row0 + cur) * H + lane], acc);
                    acc = 0.0f;
                    cur = ld;
                }
                acc += val;
            }
        }
    }
    unsafeAtomicAdd(&h[(size_t)(row0 + cur) * H + lane], acc);
}

// ------- GraphNorm + relu, in place; refresh h16; optional pool accum -------
__global__ __launch_bounds__(1024) void graphnorm_kernel(
    float* __restrict__ h, u16* __restrict__ h16,
    const int* __restrict__ start,
    const float* __restrict__ w, const float* __restrict__ b,
    const float* __restrict__ a,
    float* __restrict__ pool, int do_pool)
{
    __shared__ float red1[16][H], red2[16][H];
    __shared__ float amean_s[H], rstd_s[H];
    const int g = blockIdx.x;
    const int lane = threadIdx.x & 63;
    const int wv = threadIdx.x >> 6;
    const int s = start[g], e = start[g + 1];

    float s1 = 0.f, s2 = 0.f;
    for (int i = s + wv; i < e; i += 16) {
        float v = h[(size_t)i * H + lane];
        s1 += v; s2 += v * v;
    }
    red1[wv][lane] = s1; red2[wv][lane] = s2;
    __syncthreads();
    if (threadIdx.x < H) {
        float t1 = 0.f, t2 = 0.f;
#pragma unroll
        for (int k = 0; k < 16; ++k) { t1 += red1[k][lane]; t2 += red2[k][lane]; }
        float cnt = fmaxf((float)(e - s), 1.0f);
        float mean = t1 / cnt;
        float alpha = a[lane];
        float var = t2 / cnt - (2.0f * alpha - alpha * alpha) * mean * mean;
        var = fmaxf(var, 0.0f);
        amean_s[lane] = alpha * mean;
        rstd_s[lane] = rsqrtf(var + EPSV);
    }
    __syncthreads();
    const float am = amean_s[lane], rstd = rstd_s[lane];
    const float ww = w[lane], bb = b[lane];
    float ps = 0.f;
    for (int i = s + wv; i < e; i += 16) {
        float v = (h[(size_t)i * H + lane] - am) * rstd * ww + bb;
        v = fmaxf(v, 0.0f);
        h[(size_t)i * H + lane] = v;
        h16[(size_t)i * H + lane] = f2bf(v);
        ps += v;
    }
    if (do_pool && e > s) unsafeAtomicAdd(&pool[g * H + lane], ps);
}

// ---------------- readout from pooled sums ----------------------------------
__global__ __launch_bounds__(64) void final_kernel(
    const float* __restrict__ pool,
    const float* __restrict__ W1, const float* __restrict__ b1,
    const float* __restrict__ W2, const float* __restrict__ b2,
    float* __restrict__ out)
{
    const int g = blockIdx.x;
    const int lane = threadIdx.x;
    const float gv = pool[g * H + lane];
    float acc = b1[lane];
#pragma unroll
    for (int d = 0; d < H; ++d)
        acc = fmaf(__shfl(gv, d, 64), W1[d * H + lane], acc);
    float r = fmaxf(acc, 0.0f);
    float v = r * W2[lane];
#pragma unroll
    for (int o = 32; o > 0; o >>= 1) v += __shfl_xor(v, o, 64);
    if (lane == 0) out[g] = v + b2[0];
}

extern "C" void kernel_launch(void* const* d_in, const int* in_sizes, int n_in,
                              void* d_out, int out_size, void* d_ws, size_t ws_size,
                              hipStream_t stream)
{
    const float* x      = (const float*)d_in[0];
    const int*   ei     = (const int*)  d_in[1];
    const float* ea     = (const float*)d_in[2];
    const int*   batch  = (const int*)  d_in[3];
    const float* ligW1  = (const float*)d_in[4];
    const float* ligb1  = (const float*)d_in[5];
    const float* ligW2  = (const float*)d_in[6];
    const float* ligb2  = (const float*)d_in[7];
    const float* protW1 = (const float*)d_in[8];
    const float* protb1 = (const float*)d_in[9];
    const float* protW2 = (const float*)d_in[10];
    const float* protb2 = (const float*)d_in[11];
    const float* convWe = (const float*)d_in[12];
    const float* convbe = (const float*)d_in[13];
    const float* convW1 = (const float*)d_in[14];
    const float* convb1 = (const float*)d_in[15];
    const float* convW2 = (const float*)d_in[16];
    const float* convb2 = (const float*)d_in[17];
    const float* normw  = (const float*)d_in[18];
    const float* normb  = (const float*)d_in[19];
    const float* norma  = (const float*)d_in[20];
    const float* outW1  = (const float*)d_in[21];
    const float* outb1  = (const float*)d_in[22];
    const float* outW2  = (const float*)d_in[23];
    const float* outb2  = (const float*)d_in[24];

    float* out = (float*)d_out;

    // -------- workspace layout (16B-aligned blocks first) -------------------
    float* h         = (float*)d_ws;                    // NN*H f32      25.6 MB
    uint4* bfeat     = (uint4*)(h + (size_t)NN * H);    // NE uint4      25.6 MB
    u32*   brec      = (u32*)(bfeat + (size_t)NE);      // NE u32         6.4 MB
    u16*   h16       = (u16*)(brec + (size_t)NE);       // NN*H u16      12.8 MB
    u16*   xb        = h16 + (size_t)NN * H;            // NN*H u16      12.8 MB
    u16*   wf        = xb + (size_t)NN * H;             // 40960 u16     80 KB
    int2*  tmp       = (int2*)h;                        // NE int2 (overlay h)

    int*   ctr       = (int*)(wf + 40960);              // 2     (zeroed)
    int*   gbcount   = ctr + 2;                         // NBK   (zeroed)
    float* pool      = (float*)(gbcount + NBK);         // GNUM*H (zeroed)
    int*   gstart    = (int*)(pool + GNUM * H);         // NBK+1
    int*   gcur      = gstart + (NBK + 1);              // NBK
    int*   astart    = gcur + NBK;                      // NAGG+1
    int*   start     = astart + (NAGG + 1);             // GNUM+1
    int*   lig_list  = start + (GNUM + 1);              // NN
    int*   prot_list = lig_list + NN;                   // NN

    hipMemsetAsync(ctr, 0, ((size_t)2 + NBK + GNUM * H) * sizeof(int), stream);

    // ---- prep not touching overlays ----
    prep_w_kernel<<<(10 * 4096 + 255) / 256, 256, 0, stream>>>(
        ligW1, ligW2, protW1, protW2, convW1, convW2, wf);
    partition_kernel<<<(NN + 255) / 256, 256, 0, stream>>>(x, ctr, lig_list, prot_list);
    bounds_kernel<<<2, 256, 0, stream>>>(batch, start);

    // ---- build: coarse hist -> scan -> partition -> 1-pass sort (+ea pack) -
    bhist_kernel<<<NBLK_H, 1024, 0, stream>>>(ei, gbcount);
    bscan_kernel<<<1, 1024, 0, stream>>>(gbcount, gstart, gcur);
    p1_kernel<<<NBLK_P1, 1024, 0, stream>>>(ei, gcur, tmp);
    sort1_kernel<<<NBK, 1024, 0, stream>>>(tmp, ea, gstart, brec, bfeat, astart);

    // ---- encoder (h after tmp dead) ----
    xb_kernel<<<(NN * H + 255) / 256, 256, 0, stream>>>(x, xb);
    const int enc_blocks = (NTILE + 3) / 4;
    enc_mfma_kernel<<<enc_blocks, 256, 0, stream>>>(
        lig_list, &ctr[0], xb, wf + 0 * 4096, wf + 1 * 4096, ligb1, ligb2, h, h16);
    enc_mfma_kernel<<<enc_blocks, 256, 0, stream>>>(
        prot_list, &ctr[1], xb, wf + 2 * 4096, wf + 3 * 4096, protb1, protb2, h, h16);

    const int aggr_blocks = NAGG / 4;   // 3125, exact (one wave per 8-dst group)
    const int mlp_blocks = (NTILE + 3) / 4;
    for (int l = 0; l < 3; ++l) {
        aggr_kernel<<<aggr_blocks, 256, 0, stream>>>(
            brec, (const u32*)bfeat, astart,
            convWe + (size_t)l * EDIM * H, convbe + (size_t)l * H, h16, h);
        mlp_mfma_kernel<<<mlp_blocks, 256, 0, stream>>>(
            wf + (size_t)(4 + 2 * l) * 4096, wf + (size_t)(5 + 2 * l) * 4096,
            convb1 + (size_t)l * H, convb2 + (size_t)l * H, h);
        graphnorm_kernel<<<GNUM, 1024, 0, stream>>>(
            h, h16, start, normw + (size_t)l * H, normb + (size_t)l * H,
            norma + (size_t)l * H, pool, (l == 2) ? 1 : 0);
    }
    final_kernel<<<GNUM, 64, 0, stream>>>(pool, outW1, outb1, outW2, outb2, out);
}